// Round 10
// baseline (88.964 us; speedup 1.0000x reference)
//
#include <hip/hip_runtime.h>
#include <hip/hip_bf16.h>
#include <float.h>

#define NHEAD 8

typedef __attribute__((ext_vector_type(8))) short bf16x8;
typedef __attribute__((ext_vector_type(4))) float f32x4;

static __device__ __forceinline__ unsigned short bfb(float f) {
    __hip_bfloat16 h = __float2bfloat16(f);
    unsigned short u; __builtin_memcpy(&u, &h, 2); return u;
}
static __device__ __forceinline__ unsigned int pk2(float a, float b) {
    return (unsigned int)bfb(a) | ((unsigned int)bfb(b) << 16);
}
static __device__ __forceinline__ float bf2f_lo(unsigned int u) { return __uint_as_float(u << 16); }
static __device__ __forceinline__ float bf2f_hi(unsigned int u) { return __uint_as_float(u & 0xffff0000u); }

// sB (K_norm) / sRW (rel-weights): [256][64] u16, XOR-8 swizzle
static __device__ __forceinline__ int swz64(int r, int c) {
    return (r << 6) + (c ^ ((r & 7) << 3));
}
// V^T (lives in sB after B2): [64 c][256 kk] u16, chunk-XOR-32 (b128 rw at bank floor)
static __device__ __forceinline__ int vIdx(int c, int kk) {
    return (c << 8) + (kk ^ ((c & 31) << 3));
}
// sP: per-wave [16][40] u16 slab (80B rows), 16B-chunk XOR; col in [0,32)
static __device__ __forceinline__ int pIdx(int wv, int row, int col) {
    const int ch = (col >> 3) ^ (row & 3);
    return (wv * 16 + row) * 40 + ch * 8 + (col & 7);
}

static __device__ __forceinline__ f32x4 mfma16(bf16x8 a, bf16x8 b, f32x4 c) {
    return __builtin_amdgcn_mfma_f32_16x16x32_bf16(a, b, c, 0, 0, 0);
}

__global__ __launch_bounds__(512, 2)
void local_attn_kernel(const float* __restrict__ qg, const float* __restrict__ kg,
                       const float* __restrict__ vg, const float* __restrict__ rwg,
                       float* __restrict__ outg)
{
    __shared__ __align__(16) unsigned short sB[256 * 64];     // 32 KB: K_norm -> V^T
    __shared__ __align__(16) unsigned short sRW[256 * 64];    // 32 KB: rel-weights
    __shared__ __align__(16) unsigned short sP[8 * 16 * 40];  // 10 KB: per-wave P slabs

    const int tid  = threadIdx.x;
    const int lane = tid & 63;
    const int wv   = tid >> 6;       // 0..7
    const int jl   = lane & 15;
    const int hi   = lane >> 4;      // 0..3

    // XCD-bijective swizzle: 1024 blocks = 8 XCDs x 128
    const int lb = ((blockIdx.x & 7) << 7) + (blockIdx.x >> 3);
    const int bh = lb >> 6;
    const int n  = lb & 63;
    const int h  = bh & 7;

    const float scale = 0.125f;
    const size_t bhOff = (size_t)bh * 8192 * 64;

    const float* Qp = qg + bhOff + (size_t)n * 128 * 64;
    const float* Kp = kg + bhOff + ((long)n - 1) * 128 * 64;
    const float* Vp = vg + bhOff + ((long)n - 1) * 128 * 64;

    const int cr = tid >> 4;          // 0..31
    const int c0 = (tid & 15) << 2;   // feature group of 4

    // ---- V loads: lane = column, 32 coalesced dwords (stride 256B) ----
    const int vc  = tid & 63;
    const int vkb = (tid >> 6) << 5;          // wave covers kk = vkb..vkb+31
    const bool vzero = (n == 0 && vkb < 128); // wave-uniform
    float vx[32];
    #pragma unroll
    for (int u = 0; u < 32; ++u)
        vx[u] = vzero ? 0.f : Vp[(vkb + u) * 64 + vc];

    // ---- K -> normalize (shfl) -> sB ----
    #pragma unroll
    for (int pp = 0; pp < 8; ++pp) {
        const int row = pp * 32 + cr;
        f32x4 x = {0.f, 0.f, 0.f, 0.f};
        if (!(n == 0 && row < 128))
            x = *reinterpret_cast<const f32x4*>(Kp + row * 64 + c0);
        float ss = x[0] * x[0] + x[1] * x[1] + x[2] * x[2] + x[3] * x[3];
        ss += __shfl_xor(ss, 1);
        ss += __shfl_xor(ss, 2);
        ss += __shfl_xor(ss, 4);
        ss += __shfl_xor(ss, 8);
        const float rn = 1.0f / fmaxf(sqrtf(ss), 1e-12f);
        ushort4 pkk = make_ushort4(bfb(x[0] * rn), bfb(x[1] * rn),
                                   bfb(x[2] * rn), bfb(x[3] * rn));
        *reinterpret_cast<ushort4*>(&sB[swz64(row, c0)]) = pkk;
    }

    // ---- RW -> sRW (own region, staged once) ----
    #pragma unroll
    for (int pp = 0; pp < 8; ++pp) {
        const int row = pp * 32 + cr;
        const f32x4 x = *reinterpret_cast<const f32x4*>(rwg + ((size_t)row * NHEAD + h) * 64 + c0);
        ushort4 pkw = make_ushort4(bfb(x[0]), bfb(x[1]), bfb(x[2]), bfb(x[3]));
        *reinterpret_cast<ushort4*>(&sRW[swz64(row, c0)]) = pkw;
    }

    // ---- Q fragments direct from global ----
    const int arow = wv * 16 + jl;
    const int kq0  = hi << 3;
    const float* qr = Qp + arow * 64 + kq0;
    const f32x4 qa = *reinterpret_cast<const f32x4*>(qr);
    const f32x4 qb = *reinterpret_cast<const f32x4*>(qr + 4);
    const f32x4 qc = *reinterpret_cast<const f32x4*>(qr + 32);
    const f32x4 qd = *reinterpret_cast<const f32x4*>(qr + 36);
    bf16x8 aq0, aq1;
    #pragma unroll
    for (int q = 0; q < 4; ++q) {
        aq0[q]     = (short)bfb(qa[q] * scale);
        aq0[q + 4] = (short)bfb(qb[q] * scale);
        aq1[q]     = (short)bfb(qc[q] * scale);
        aq1[q + 4] = (short)bfb(qd[q] * scale);
    }

    // ---- pack V to 16 uints (held across fused phase) ----
    unsigned int vpk[16];
    #pragma unroll
    for (int u = 0; u < 16; ++u)
        vpk[u] = pk2(vx[2 * u], vx[2 * u + 1]);
    #pragma unroll
    for (int u = 0; u < 16; ++u)
        asm volatile("" :: "v"(vpk[u]));  // keep-alive: don't re-sink loads

    __syncthreads();  // B1: K_norm + RW staged

    const int ibase = wv * 16 + (hi << 2);
    const int tMax  = wv + 8;

    // ---- FUSED phase: QK^T + emb (rolling 2 slots) + bias, one barrier-free chain ----
    const int cv0 = 4 * hi + 1, cv1 = 4 * hi + 2, cv2 = 4 * hi + 3, cv3 = 4 * hi + 4;
    const int sl0 = (hi << 4) | ((jl - cv0) & 15);
    const int sl1 = (hi << 4) | ((jl - cv1) & 15);
    const int sl2 = (hi << 4) | ((jl - cv2) & 15);
    const int sl3 = (hi << 4) | ((jl - cv3) & 15);
    const bool g0 = jl >= cv0, g1 = jl >= cv1, g2 = jl >= cv2, g3 = jl >= cv3;

    unsigned int cur01, cur23;
    {
        const int rr = (7 - wv) * 16 + jl;   // slot 0 = rel-tile 7-wv (always valid)
        const bf16x8 b0 = *reinterpret_cast<const bf16x8*>(&sRW[swz64(rr, kq0)]);
        const bf16x8 b1 = *reinterpret_cast<const bf16x8*>(&sRW[swz64(rr, 32 + kq0)]);
        f32x4 e = {0.f, 0.f, 0.f, 0.f};
        e = mfma16(aq0, b0, e);
        e = mfma16(aq1, b1, e);
        cur01 = pk2(e[0], e[1]);
        cur23 = pk2(e[2], e[3]);
    }
    unsigned int lo0 = (unsigned int)__shfl((int)cur01, sl0);
    unsigned int lo1 = (unsigned int)__shfl((int)cur01, sl1);
    unsigned int lo2 = (unsigned int)__shfl((int)cur23, sl2);
    unsigned int lo3 = (unsigned int)__shfl((int)cur23, sl3);

    f32x4 dots[16] = {};
    #pragma unroll
    for (int t = 0; t < 16; ++t) {
        if (t <= tMax) {
            // QK tile t
            const int rr = t * 16 + jl;
            const bf16x8 b0 = *reinterpret_cast<const bf16x8*>(&sB[swz64(rr, kq0)]);
            const bf16x8 b1 = *reinterpret_cast<const bf16x8*>(&sB[swz64(rr, 32 + kq0)]);
            f32x4 d = {0.f, 0.f, 0.f, 0.f};
            d = mfma16(aq0, b0, d);
            d = mfma16(aq1, b1, d);
            // emb slot t+1 = rel-tile t+8-wv
            unsigned int n01 = 0, n23 = 0;
            const int ts = t + 8 - wv;
            if (ts < 16) {
                const int rr2 = ts * 16 + jl;
                const bf16x8 e0 = *reinterpret_cast<const bf16x8*>(&sRW[swz64(rr2, kq0)]);
                const bf16x8 e1 = *reinterpret_cast<const bf16x8*>(&sRW[swz64(rr2, 32 + kq0)]);
                f32x4 e = {0.f, 0.f, 0.f, 0.f};
                e = mfma16(aq0, e0, e);
                e = mfma16(aq1, e1, e);
                n01 = pk2(e[0], e[1]);
                n23 = pk2(e[2], e[3]);
            }
            const unsigned int h0 = (unsigned int)__shfl((int)n01, sl0);
            const unsigned int h1 = (unsigned int)__shfl((int)n01, sl1);
            const unsigned int h2 = (unsigned int)__shfl((int)n23, sl2);
            const unsigned int h3 = (unsigned int)__shfl((int)n23, sl3);
            d[0] += bf2f_lo(g0 ? h0 : lo0);
            d[1] += bf2f_hi(g1 ? h1 : lo1);
            d[2] += bf2f_lo(g2 ? h2 : lo2);
            d[3] += bf2f_hi(g3 ? h3 : lo3);
            dots[t] = d;
            lo0 = h0; lo1 = h1; lo2 = h2; lo3 = h3;
        }
    }

    // ---- masks (only t == tMax can have dd >= 128) ----
    #pragma unroll
    for (int tt = 8; tt <= 15; ++tt) {
        if (tt == tMax) {
            #pragma unroll
            for (int r = 0; r < 4; ++r) {
                const int dd = 128 + jl - 4 * hi - r;
                float x = dots[tt][r];
                x = (dd == 128) ? -50.0f : x;   // self (exp=2e-22 keeps token-0 row alive)
                x = (dd > 128) ? -3.0e38f : x;  // causal
                dots[tt][r] = x;
            }
        }
    }
    if (n == 0) {
        #pragma unroll
        for (int t = 0; t < 8; ++t)
            #pragma unroll
            for (int r = 0; r < 4; ++r)
                dots[t][r] = -3.0e38f;
    }

    // ---- softmax denominators BEFORE the barrier ----
    float sm[4] = {0.f, 0.f, 0.f, 0.f};
    #pragma unroll
    for (int t = 0; t < 16; ++t) {
        if (t <= tMax) {
            #pragma unroll
            for (int r = 0; r < 4; ++r) {
                const float pe = __expf(dots[t][r]);
                dots[t][r] = pe;
                sm[r] += pe;
            }
        }
    }
    float rinv[4];
    #pragma unroll
    for (int r = 0; r < 4; ++r) {
        sm[r] += __shfl_xor(sm[r], 1);
        sm[r] += __shfl_xor(sm[r], 2);
        sm[r] += __shfl_xor(sm[r], 4);
        sm[r] += __shfl_xor(sm[r], 8);
        rinv[r] = 1.0f / sm[r];
    }

    __syncthreads();  // B2: all QK reads of sB done

    // ---- V dump: 4 x b128 into kk-contiguous [64][256] layout ----
    #pragma unroll
    for (int w4 = 0; w4 < 4; ++w4) {
        const uint4 w = make_uint4(vpk[4 * w4], vpk[4 * w4 + 1],
                                   vpk[4 * w4 + 2], vpk[4 * w4 + 3]);
        *reinterpret_cast<uint4*>(&sB[vIdx(vc, vkb + 8 * w4)]) = w;
    }

    __syncthreads();  // B3: V^T ready

    // ---- PV: per-wave P slab; V fragments = single b128 each ----
    f32x4 o[4] = {};
    #pragma unroll
    for (int pv = 0; pv < 8; ++pv) {
        if (2 * pv <= tMax) {
            #pragma unroll
            for (int tt = 0; tt < 2; ++tt) {
                const int t = 2 * pv + tt;
                #pragma unroll
                for (int r = 0; r < 4; ++r) {
                    unsigned short val = 0;
                    if (t <= tMax) val = bfb(dots[t][r]);
                    sP[pIdx(wv, 4 * hi + r, tt * 16 + jl)] = val;
                }
            }
            const bf16x8 pa = *reinterpret_cast<const bf16x8*>(&sP[pIdx(wv, jl, kq0)]);
            __builtin_amdgcn_s_setprio(1);
            #pragma unroll
            for (int ct = 0; ct < 4; ++ct) {
                const bf16x8 vb = *reinterpret_cast<const bf16x8*>(&sB[vIdx(ct * 16 + jl, pv * 32 + kq0)]);
                o[ct] = mfma16(pa, vb, o[ct]);
            }
            __builtin_amdgcn_s_setprio(0);
        }
    }

    // ---- epilogue ----
    float* Op = outg + bhOff + (size_t)n * 128 * 64;
    #pragma unroll
    for (int ct = 0; ct < 4; ++ct)
        #pragma unroll
        for (int r = 0; r < 4; ++r)
            Op[(ibase + r) * 64 + ct * 16 + jl] = o[ct][r] * rinv[r];
}

extern "C" void kernel_launch(void* const* d_in, const int* in_sizes, int n_in,
                              void* d_out, int out_size, void* d_ws, size_t ws_size,
                              hipStream_t stream) {
    const float* q  = (const float*)d_in[0];
    const float* k  = (const float*)d_in[1];
    const float* v  = (const float*)d_in[2];
    const float* rw = (const float*)d_in[3];
    float* out = (float*)d_out;
    local_attn_kernel<<<dim3(1024), dim3(512), 0, stream>>>(q, k, v, rw, out);
}

// Round 11
// 56.247 us; speedup vs baseline: 1.5817x; 1.5817x over previous
//
#include <hip/hip_runtime.h>
#include <hip/hip_bf16.h>
#include <float.h>

#define NHEAD 8

typedef __attribute__((ext_vector_type(8))) short bf16x8;
typedef __attribute__((ext_vector_type(4))) float f32x4;

static __device__ __forceinline__ unsigned short bfb(float f) {
    __hip_bfloat16 h = __float2bfloat16(f);
    unsigned short u; __builtin_memcpy(&u, &h, 2); return u;
}
static __device__ __forceinline__ unsigned int pk2(float a, float b) {
    return (unsigned int)bfb(a) | ((unsigned int)bfb(b) << 16);
}
static __device__ __forceinline__ float bf2f_lo(unsigned int u) { return __uint_as_float(u << 16); }
static __device__ __forceinline__ float bf2f_hi(unsigned int u) { return __uint_as_float(u & 0xffff0000u); }

// sB (K_norm) / sRW (rel-weights): [256][64] u16, XOR-8 swizzle
static __device__ __forceinline__ int swz64(int r, int c) {
    return (r << 6) + (c ^ ((r & 7) << 3));
}
// V^T (lives in sB after B2): [64 c][256 kk] u16, chunk-XOR-32 (b128 rw at bank floor)
static __device__ __forceinline__ int vIdx(int c, int kk) {
    return (c << 8) + (kk ^ ((c & 31) << 3));
}
// sP: per-wave [16][40] u16 slab (80B rows), 16B-chunk XOR; col in [0,32)
static __device__ __forceinline__ int pIdx(int wv, int row, int col) {
    const int ch = (col >> 3) ^ (row & 3);
    return (wv * 16 + row) * 40 + ch * 8 + (col & 7);
}

static __device__ __forceinline__ f32x4 mfma16(bf16x8 a, bf16x8 b, f32x4 c) {
    return __builtin_amdgcn_mfma_f32_16x16x32_bf16(a, b, c, 0, 0, 0);
}

__global__ __launch_bounds__(512) __attribute__((amdgpu_waves_per_eu(4)))
void local_attn_kernel(const float* __restrict__ qg, const float* __restrict__ kg,
                       const float* __restrict__ vg, const float* __restrict__ rwg,
                       float* __restrict__ outg)
{
    __shared__ __align__(16) unsigned short sB[256 * 64];     // 32 KB: K_norm -> V^T
    __shared__ __align__(16) unsigned short sRW[256 * 64];    // 32 KB: rel-weights
    __shared__ __align__(16) unsigned short sP[8 * 16 * 40];  // 10 KB: per-wave P slabs

    const int tid  = threadIdx.x;
    const int lane = tid & 63;
    const int wv   = tid >> 6;       // 0..7
    const int jl   = lane & 15;
    const int hi   = lane >> 4;      // 0..3

    // XCD-bijective swizzle: 1024 blocks = 8 XCDs x 128
    const int lb = ((blockIdx.x & 7) << 7) + (blockIdx.x >> 3);
    const int bh = lb >> 6;
    const int n  = lb & 63;
    const int h  = bh & 7;

    const float scale = 0.125f;
    const size_t bhOff = (size_t)bh * 8192 * 64;

    const float* Qp = qg + bhOff + (size_t)n * 128 * 64;
    const float* Kp = kg + bhOff + ((long)n - 1) * 128 * 64;
    const float* Vp = vg + bhOff + ((long)n - 1) * 128 * 64;

    const int cr = tid >> 4;          // 0..31
    const int c0 = (tid & 15) << 2;   // feature group of 4

    // ---- V loads: lane = column, packed pairwise at load (<=2 floats transient) ----
    const int vc  = tid & 63;
    const int vkb = (tid >> 6) << 5;          // wave covers kk = vkb..vkb+31
    const bool vzero = (n == 0 && vkb < 128); // wave-uniform
    unsigned int vpk[16];
    #pragma unroll
    for (int u = 0; u < 16; ++u) {
        float a = 0.f, b = 0.f;
        if (!vzero) {
            a = Vp[(vkb + 2 * u) * 64 + vc];
            b = Vp[(vkb + 2 * u + 1) * 64 + vc];
        }
        vpk[u] = pk2(a, b);
    }
    #pragma unroll
    for (int u = 0; u < 16; ++u)
        asm volatile("" :: "v"(vpk[u]));  // keep-alive: don't re-sink loads

    // ---- K -> normalize (shfl) -> sB ----
    #pragma unroll
    for (int pp = 0; pp < 8; ++pp) {
        const int row = pp * 32 + cr;
        f32x4 x = {0.f, 0.f, 0.f, 0.f};
        if (!(n == 0 && row < 128))
            x = *reinterpret_cast<const f32x4*>(Kp + row * 64 + c0);
        float ss = x[0] * x[0] + x[1] * x[1] + x[2] * x[2] + x[3] * x[3];
        ss += __shfl_xor(ss, 1);
        ss += __shfl_xor(ss, 2);
        ss += __shfl_xor(ss, 4);
        ss += __shfl_xor(ss, 8);
        const float rn = 1.0f / fmaxf(sqrtf(ss), 1e-12f);
        ushort4 pkk = make_ushort4(bfb(x[0] * rn), bfb(x[1] * rn),
                                   bfb(x[2] * rn), bfb(x[3] * rn));
        *reinterpret_cast<ushort4*>(&sB[swz64(row, c0)]) = pkk;
    }

    // ---- RW -> sRW (own region, staged once) ----
    #pragma unroll
    for (int pp = 0; pp < 8; ++pp) {
        const int row = pp * 32 + cr;
        const f32x4 x = *reinterpret_cast<const f32x4*>(rwg + ((size_t)row * NHEAD + h) * 64 + c0);
        ushort4 pkw = make_ushort4(bfb(x[0]), bfb(x[1]), bfb(x[2]), bfb(x[3]));
        *reinterpret_cast<ushort4*>(&sRW[swz64(row, c0)]) = pkw;
    }

    // ---- Q fragments direct from global ----
    const int arow = wv * 16 + jl;
    const int kq0  = hi << 3;
    const float* qr = Qp + arow * 64 + kq0;
    const f32x4 qa = *reinterpret_cast<const f32x4*>(qr);
    const f32x4 qb = *reinterpret_cast<const f32x4*>(qr + 4);
    const f32x4 qc = *reinterpret_cast<const f32x4*>(qr + 32);
    const f32x4 qd = *reinterpret_cast<const f32x4*>(qr + 36);
    bf16x8 aq0, aq1;
    #pragma unroll
    for (int q = 0; q < 4; ++q) {
        aq0[q]     = (short)bfb(qa[q] * scale);
        aq0[q + 4] = (short)bfb(qb[q] * scale);
        aq1[q]     = (short)bfb(qc[q] * scale);
        aq1[q + 4] = (short)bfb(qd[q] * scale);
    }

    __syncthreads();  // B1: K_norm + RW staged

    const int tMax = wv + 8;

    // ---- FUSED phase: QK^T + emb + bias + masks + exp + pack, per tile ----
    const int cv0 = 4 * hi + 1, cv1 = 4 * hi + 2, cv2 = 4 * hi + 3, cv3 = 4 * hi + 4;
    const int sl0 = (hi << 4) | ((jl - cv0) & 15);
    const int sl1 = (hi << 4) | ((jl - cv1) & 15);
    const int sl2 = (hi << 4) | ((jl - cv2) & 15);
    const int sl3 = (hi << 4) | ((jl - cv3) & 15);
    const bool g0 = jl >= cv0, g1 = jl >= cv1, g2 = jl >= cv2, g3 = jl >= cv3;

    unsigned int cur01, cur23;
    {
        const int rr = (7 - wv) * 16 + jl;   // slot 0 = rel-tile 7-wv (always valid)
        const bf16x8 b0 = *reinterpret_cast<const bf16x8*>(&sRW[swz64(rr, kq0)]);
        const bf16x8 b1 = *reinterpret_cast<const bf16x8*>(&sRW[swz64(rr, 32 + kq0)]);
        f32x4 e = {0.f, 0.f, 0.f, 0.f};
        e = mfma16(aq0, b0, e);
        e = mfma16(aq1, b1, e);
        cur01 = pk2(e[0], e[1]);
        cur23 = pk2(e[2], e[3]);
    }
    unsigned int lo0 = (unsigned int)__shfl((int)cur01, sl0);
    unsigned int lo1 = (unsigned int)__shfl((int)cur01, sl1);
    unsigned int lo2 = (unsigned int)__shfl((int)cur23, sl2);
    unsigned int lo3 = (unsigned int)__shfl((int)cur23, sl3);

    unsigned int p01[16] = {}, p23[16] = {};
    float sm[4] = {0.f, 0.f, 0.f, 0.f};
    const bool npad = (n == 0);

    #pragma unroll
    for (int t = 0; t < 16; ++t) {
        if (t <= tMax) {
            // QK tile t
            const int rr = t * 16 + jl;
            const bf16x8 b0 = *reinterpret_cast<const bf16x8*>(&sB[swz64(rr, kq0)]);
            const bf16x8 b1 = *reinterpret_cast<const bf16x8*>(&sB[swz64(rr, 32 + kq0)]);
            f32x4 d = {0.f, 0.f, 0.f, 0.f};
            d = mfma16(aq0, b0, d);
            d = mfma16(aq1, b1, d);
            // emb slot t+1 = rel-tile t+8-wv
            unsigned int n01 = 0, n23 = 0;
            const int ts = t + 8 - wv;
            if (ts < 16) {
                const int rr2 = ts * 16 + jl;
                const bf16x8 e0 = *reinterpret_cast<const bf16x8*>(&sRW[swz64(rr2, kq0)]);
                const bf16x8 e1 = *reinterpret_cast<const bf16x8*>(&sRW[swz64(rr2, 32 + kq0)]);
                f32x4 e = {0.f, 0.f, 0.f, 0.f};
                e = mfma16(aq0, e0, e);
                e = mfma16(aq1, e1, e);
                n01 = pk2(e[0], e[1]);
                n23 = pk2(e[2], e[3]);
            }
            const unsigned int h0 = (unsigned int)__shfl((int)n01, sl0);
            const unsigned int h1 = (unsigned int)__shfl((int)n01, sl1);
            const unsigned int h2 = (unsigned int)__shfl((int)n23, sl2);
            const unsigned int h3 = (unsigned int)__shfl((int)n23, sl3);
            d[0] += bf2f_lo(g0 ? h0 : lo0);
            d[1] += bf2f_hi(g1 ? h1 : lo1);
            d[2] += bf2f_lo(g2 ? h2 : lo2);
            d[3] += bf2f_hi(g3 ? h3 : lo3);
            lo0 = h0; lo1 = h1; lo2 = h2; lo3 = h3;
            // masks: only t == tMax can have dd >= 128; n==0 pads tiles 0..7
            if (t >= 8 && t == tMax) {
                #pragma unroll
                for (int r = 0; r < 4; ++r) {
                    const int dd = 128 + jl - 4 * hi - r;
                    float x = d[r];
                    x = (dd == 128) ? -50.0f : x;   // self (exp=2e-22 keeps token-0 row alive)
                    x = (dd > 128) ? -3.0e38f : x;  // causal
                    d[r] = x;
                }
            }
            if (t < 8 && npad) {
                #pragma unroll
                for (int r = 0; r < 4; ++r) d[r] = -3.0e38f;
            }
            // exp + accumulate + pack to bf16 immediately (frees the f32x4)
            f32x4 pe;
            #pragma unroll
            for (int r = 0; r < 4; ++r) {
                pe[r] = __expf(d[r]);
                sm[r] += pe[r];
            }
            p01[t] = pk2(pe[0], pe[1]);
            p23[t] = pk2(pe[2], pe[3]);
        }
    }

    float rinv[4];
    #pragma unroll
    for (int r = 0; r < 4; ++r) {
        sm[r] += __shfl_xor(sm[r], 1);
        sm[r] += __shfl_xor(sm[r], 2);
        sm[r] += __shfl_xor(sm[r], 4);
        sm[r] += __shfl_xor(sm[r], 8);
        rinv[r] = 1.0f / sm[r];
    }

    __syncthreads();  // B2: all QK reads of sB done

    // ---- V dump: 4 x b128 into kk-contiguous [64][256] layout ----
    #pragma unroll
    for (int w4 = 0; w4 < 4; ++w4) {
        const uint4 w = make_uint4(vpk[4 * w4], vpk[4 * w4 + 1],
                                   vpk[4 * w4 + 2], vpk[4 * w4 + 3]);
        *reinterpret_cast<uint4*>(&sB[vIdx(vc, vkb + 8 * w4)]) = w;
    }

    __syncthreads();  // B3: V^T ready

    // ---- PV: per-wave P slab; V fragments = single b128 each ----
    f32x4 o[4] = {};
    #pragma unroll
    for (int pv = 0; pv < 8; ++pv) {
        if (2 * pv <= tMax) {
            #pragma unroll
            for (int tt = 0; tt < 2; ++tt) {
                const int t = 2 * pv + tt;
                const unsigned int w01 = p01[t];
                const unsigned int w23 = p23[t];
                const int col = tt * 16 + jl;
                sP[pIdx(wv, 4 * hi + 0, col)] = (unsigned short)w01;
                sP[pIdx(wv, 4 * hi + 1, col)] = (unsigned short)(w01 >> 16);
                sP[pIdx(wv, 4 * hi + 2, col)] = (unsigned short)w23;
                sP[pIdx(wv, 4 * hi + 3, col)] = (unsigned short)(w23 >> 16);
            }
            const bf16x8 pa = *reinterpret_cast<const bf16x8*>(&sP[pIdx(wv, jl, kq0)]);
            __builtin_amdgcn_s_setprio(1);
            #pragma unroll
            for (int ct = 0; ct < 4; ++ct) {
                const bf16x8 vb = *reinterpret_cast<const bf16x8*>(&sB[vIdx(ct * 16 + jl, pv * 32 + kq0)]);
                o[ct] = mfma16(pa, vb, o[ct]);
            }
            __builtin_amdgcn_s_setprio(0);
        }
    }

    // ---- epilogue ----
    const int ibase = wv * 16 + (hi << 2);
    float* Op = outg + bhOff + (size_t)n * 128 * 64;
    #pragma unroll
    for (int ct = 0; ct < 4; ++ct)
        #pragma unroll
        for (int r = 0; r < 4; ++r)
            Op[(ibase + r) * 64 + ct * 16 + jl] = o[ct][r] * rinv[r];
}

extern "C" void kernel_launch(void* const* d_in, const int* in_sizes, int n_in,
                              void* d_out, int out_size, void* d_ws, size_t ws_size,
                              hipStream_t stream) {
    const float* q  = (const float*)d_in[0];
    const float* k  = (const float*)d_in[1];
    const float* v  = (const float*)d_in[2];
    const float* rw = (const float*)d_in[3];
    float* out = (float*)d_out;
    local_attn_kernel<<<dim3(1024), dim3(512), 0, stream>>>(q, k, v, rw, out);
}